// Round 1
// baseline (142.383 us; speedup 1.0000x reference)
//
#include <hip/hip_runtime.h>
#include <hip/hip_bf16.h>
#include <math.h>

#define TPB 256
#define JCH 16   // j-chunks: grid.y; partials in ws

#if defined(__has_builtin)
#  if __has_builtin(__builtin_amdgcn_exp2f)
#    define EXP2F(x) __builtin_amdgcn_exp2f(x)
#  else
#    define EXP2F(x) exp2f(x)
#  endif
#else
#  define EXP2F(x) exp2f(x)
#endif

// Normalize velocities, pre-scale by sqrt(log2(e)) so dot(w_i, w_j) = s_ij * log2(e).
// Also zero-initializes the output accumulator.
__global__ __launch_bounds__(TPB) void prep_kernel(const float* __restrict__ v,
                                                   float4* __restrict__ U,
                                                   float* __restrict__ out, int N) {
    int i = blockIdx.x * TPB + threadIdx.x;
    if (i == 0 && blockIdx.x == 0) out[0] = 0.0f;
    if (i < N) {
        float x = v[3 * i + 0], y = v[3 * i + 1], z = v[3 * i + 2];
        float n = sqrtf(x * x + y * y + z * z) + 1e-6f;
        float s = 1.2011224087864498f / n;  // sqrt(log2(e)) / (|v| + 1e-6)
        U[i] = make_float4(x * s, y * s, z * s, 0.0f);
    }
}

// Each thread owns one row i; iterates a wave-uniform j-chunk.
// Accumulates Z = sum exp2(t), S' = sum t*exp2(t)  (t = s * log2 e).
__global__ __launch_bounds__(TPB) void pair_kernel(const float4* __restrict__ U,
                                                   float* __restrict__ partZ,
                                                   float* __restrict__ partS, int N) {
    int row = blockIdx.x * TPB + threadIdx.x;
    if (row >= N) return;
    int chunk = blockIdx.y;
    int len = N / JCH;
    int j0 = chunk * len;
    int j1 = j0 + len;
    if (j1 > N) j1 = N;

    float4 w = U[row];
    float wx = w.x, wy = w.y, wz = w.z;

    float Z0 = 0.f, Z1 = 0.f, Z2 = 0.f, Z3 = 0.f;
    float S0 = 0.f, S1 = 0.f, S2 = 0.f, S3 = 0.f;

    int j = j0;
    for (; j + 3 < j1; j += 4) {
        float4 a = U[j + 0];
        float4 b = U[j + 1];
        float4 c = U[j + 2];
        float4 d = U[j + 3];
        float t0 = fmaf(wx, a.x, fmaf(wy, a.y, wz * a.z));
        float t1 = fmaf(wx, b.x, fmaf(wy, b.y, wz * b.z));
        float t2 = fmaf(wx, c.x, fmaf(wy, c.y, wz * c.z));
        float t3 = fmaf(wx, d.x, fmaf(wy, d.y, wz * d.z));
        float e0 = EXP2F(t0);
        float e1 = EXP2F(t1);
        float e2 = EXP2F(t2);
        float e3 = EXP2F(t3);
        Z0 += e0; Z1 += e1; Z2 += e2; Z3 += e3;
        S0 = fmaf(t0, e0, S0);
        S1 = fmaf(t1, e1, S1);
        S2 = fmaf(t2, e2, S2);
        S3 = fmaf(t3, e3, S3);
    }
    for (; j < j1; ++j) {  // tail (not taken for N=16384)
        float4 a = U[j];
        float t0 = fmaf(wx, a.x, fmaf(wy, a.y, wz * a.z));
        float e0 = EXP2F(t0);
        Z0 += e0;
        S0 = fmaf(t0, e0, S0);
    }

    partZ[chunk * N + row] = (Z0 + Z1) + (Z2 + Z3);
    partS[chunk * N + row] = (S0 + S1) + (S2 + S3);
}

// Reduce partials per row, compute entropy, mean-reduce into out[0].
__global__ __launch_bounds__(TPB) void final_kernel(const float* __restrict__ partZ,
                                                    const float* __restrict__ partS,
                                                    float* __restrict__ out, int N) {
    int row = blockIdx.x * TPB + threadIdx.x;
    float contrib = 0.0f;
    if (row < N) {
        float Z = 0.f, S = 0.f;
        for (int c = 0; c < JCH; ++c) {
            Z += partZ[c * N + row];
            S += partS[c * N + row];
        }
        const float LN2 = 0.6931471805599453f;
        // H = ln Z - (S_nat / Z) - eps*N ;  S_nat = ln2 * S'  ; ln Z = ln2 * log2 Z
        float H = LN2 * (log2f(Z) - S / Z) - 1e-8f * (float)N;
        contrib = H / (float)N;
    }
    // wave reduce (64 lanes)
    for (int off = 32; off > 0; off >>= 1)
        contrib += __shfl_down(contrib, off);
    __shared__ float red[TPB / 64];
    int lane = threadIdx.x & 63;
    int wave = threadIdx.x >> 6;
    if (lane == 0) red[wave] = contrib;
    __syncthreads();
    if (threadIdx.x == 0) {
        float s = 0.f;
        for (int wv = 0; wv < TPB / 64; ++wv) s += red[wv];
        atomicAdd(out, s);
    }
}

extern "C" void kernel_launch(void* const* d_in, const int* in_sizes, int n_in,
                              void* d_out, int out_size, void* d_ws, size_t ws_size,
                              hipStream_t stream) {
    const float* vel = (const float*)d_in[0];
    // d_in[1] (positions) is unused by the reference math.
    int N = in_sizes[0] / 3;
    float* out = (float*)d_out;

    char* ws = (char*)d_ws;
    float4* U = (float4*)ws;                                   // N * 16 B
    float* partZ = (float*)(ws + (size_t)N * sizeof(float4));  // JCH * N floats
    float* partS = partZ + (size_t)JCH * N;                    // JCH * N floats

    int nb = (N + TPB - 1) / TPB;
    prep_kernel<<<nb, TPB, 0, stream>>>(vel, U, out, N);
    dim3 grid(nb, JCH);
    pair_kernel<<<grid, TPB, 0, stream>>>(U, partZ, partS, N);
    final_kernel<<<nb, TPB, 0, stream>>>(partZ, partS, out, N);
}

// Round 2
// 97.920 us; speedup vs baseline: 1.4541x; 1.4541x over previous
//
#include <hip/hip_runtime.h>
#include <hip/hip_bf16.h>
#include <math.h>

#define TPB 256
#define ROWS 4     // rows per thread: each wave-uniform U[j] load feeds 4 dot+exp
#define JCH 128    // j-chunks (grid.y): 16 x 128 = 2048 blocks = 8 wg/CU = 100% occ

#if defined(__has_builtin)
#  if __has_builtin(__builtin_amdgcn_exp2f)
#    define EXP2F(x) __builtin_amdgcn_exp2f(x)
#  else
#    define EXP2F(x) exp2f(x)
#  endif
#else
#  define EXP2F(x) exp2f(x)
#endif

// Normalize velocities, pre-scale by sqrt(log2(e)) so dot(w_i, w_j) = s_ij * log2(e).
// Zero the per-row Z/S accumulators and the output.
__global__ __launch_bounds__(TPB) void prep_kernel(const float* __restrict__ v,
                                                   float4* __restrict__ U,
                                                   float* __restrict__ Zacc,
                                                   float* __restrict__ Sacc,
                                                   float* __restrict__ out, int N) {
    int i = blockIdx.x * TPB + threadIdx.x;
    if (i == 0) out[0] = 0.0f;
    if (i < N) {
        float x = v[3 * i + 0], y = v[3 * i + 1], z = v[3 * i + 2];
        float n = sqrtf(x * x + y * y + z * z) + 1e-6f;
        float s = 1.2011224087864498f / n;  // sqrt(log2(e)) / (|v| + 1e-6)
        U[i] = make_float4(x * s, y * s, z * s, 0.0f);
        Zacc[i] = 0.0f;
        Sacc[i] = 0.0f;
    }
}

// Each thread owns ROWS rows; iterates a wave-uniform j-chunk (scalar loads).
// Accumulates Z = sum exp2(t), S' = sum t*exp2(t)  (t = s * log2 e) per row,
// then atomically folds into the per-row accumulators.
__global__ __launch_bounds__(TPB) void pair_kernel(const float4* __restrict__ U,
                                                   float* __restrict__ Zacc,
                                                   float* __restrict__ Sacc, int N) {
    int tid = threadIdx.x;
    int base = blockIdx.x * (TPB * ROWS) + tid;  // rows: base + k*TPB
    int len = N / JCH;
    int j0 = blockIdx.y * len;

    float wx[ROWS], wy[ROWS], wz[ROWS];
#pragma unroll
    for (int k = 0; k < ROWS; ++k) {
        float4 w = U[base + k * TPB];
        wx[k] = w.x; wy[k] = w.y; wz[k] = w.z;
    }

    float Z[ROWS], S[ROWS];
#pragma unroll
    for (int k = 0; k < ROWS; ++k) { Z[k] = 0.0f; S[k] = 0.0f; }

#pragma unroll 4
    for (int j = j0; j < j0 + len; ++j) {
        float4 a = U[j];  // wave-uniform -> scalar load
#pragma unroll
        for (int k = 0; k < ROWS; ++k) {
            float t = fmaf(wx[k], a.x, fmaf(wy[k], a.y, wz[k] * a.z));
            float e = EXP2F(t);
            Z[k] += e;
            S[k] = fmaf(t, e, S[k]);
        }
    }

#pragma unroll
    for (int k = 0; k < ROWS; ++k) {
        atomicAdd(&Zacc[base + k * TPB], Z[k]);
        atomicAdd(&Sacc[base + k * TPB], S[k]);
    }
}

// Per-row entropy, then mean-reduce into out[0].
__global__ __launch_bounds__(TPB) void final_kernel(const float* __restrict__ Zacc,
                                                    const float* __restrict__ Sacc,
                                                    float* __restrict__ out, int N) {
    int row = blockIdx.x * TPB + threadIdx.x;
    float contrib = 0.0f;
    if (row < N) {
        float Z = Zacc[row];
        float S = Sacc[row];
        const float LN2 = 0.6931471805599453f;
        // H = ln Z - S_nat/Z - eps*N ;  S_nat = ln2 * S' ;  ln Z = ln2 * log2 Z
        float H = LN2 * (log2f(Z) - S / Z) - 1e-8f * (float)N;
        contrib = H / (float)N;
    }
    for (int off = 32; off > 0; off >>= 1)
        contrib += __shfl_down(contrib, off);
    __shared__ float red[TPB / 64];
    int lane = threadIdx.x & 63;
    int wave = threadIdx.x >> 6;
    if (lane == 0) red[wave] = contrib;
    __syncthreads();
    if (threadIdx.x == 0) {
        float s = 0.f;
        for (int wv = 0; wv < TPB / 64; ++wv) s += red[wv];
        atomicAdd(out, s);
    }
}

extern "C" void kernel_launch(void* const* d_in, const int* in_sizes, int n_in,
                              void* d_out, int out_size, void* d_ws, size_t ws_size,
                              hipStream_t stream) {
    const float* vel = (const float*)d_in[0];
    // d_in[1] (positions) is unused by the reference math.
    int N = in_sizes[0] / 3;
    float* out = (float*)d_out;

    char* ws = (char*)d_ws;
    float4* U = (float4*)ws;                                    // N * 16 B
    float* Zacc = (float*)(ws + (size_t)N * sizeof(float4));    // N floats
    float* Sacc = Zacc + N;                                     // N floats

    int nb = (N + TPB - 1) / TPB;
    prep_kernel<<<nb, TPB, 0, stream>>>(vel, U, Zacc, Sacc, out, N);
    dim3 grid(N / (TPB * ROWS), JCH);
    pair_kernel<<<grid, TPB, 0, stream>>>(U, Zacc, Sacc, N);
    final_kernel<<<nb, TPB, 0, stream>>>(Zacc, Sacc, out, N);
}